// Round 1
// baseline (815.072 us; speedup 1.0000x reference)
//
#include <hip/hip_runtime.h>
#include <stdint.h>

// Sparse 5x5x5 conv (N=500k, 32->32ch, 125 taps) + BatchNorm + ELU + Linear.
// R3: k_conv gathers go global->LDS via __builtin_amdgcn_global_load_lds
// (per-lane global addr, lane-linear LDS dest == A-frag layout). 4-deep
// 8KB-slot LDS ring per wave (32KB/wave, 128KB/block) keeps 3 tap-groups
// (24 x 1KB loads) in flight per wave; hand-counted s_waitcnt vmcnt(24)
// synchronizes (counts only gl_lds ops -> robust to plain-load motion).
// Invalid neighbors load from a zeroed 64B page so counts stay uniform.
// nbr index loads are now one dwordx4 per tile per 16-tap window.

#define NV 500000
#define KT 125
#define CH 32
#define EPSBN 1e-5f
#define NTILES (NV / 16)   // 31250

typedef __attribute__((ext_vector_type(8))) short short8;   // 8 x bf16 frag
typedef __attribute__((ext_vector_type(4))) float f32x4;    // MFMA C/D frag
typedef __attribute__((ext_vector_type(4), aligned(4))) int int4a; // dword-aligned int4

__device__ __forceinline__ unsigned short f2bf(float f) {
    union { float f; unsigned int u; } v; v.f = f;
    unsigned int u = v.u;
    return (unsigned short)((u + 0x7fffu + ((u >> 16) & 1u)) >> 16);  // RNE
}

__device__ __forceinline__ void gload_lds16(const void* g, void* l) {
    __builtin_amdgcn_global_load_lds(
        (const __attribute__((address_space(1))) unsigned int*)g,
        (__attribute__((address_space(3))) unsigned int*)l, 16, 0, 0);
}

// K1: x -> bf16 (vectorized); W_conv B-frags (wf); W_lin^T B-frags (wl);
// zero stats + 128B zero-page (gather target for missing neighbors).
__global__ __launch_bounds__(256) void
k_prep(const float* __restrict__ x, const float* __restrict__ Wc,
       const float* __restrict__ Wlin,
       unsigned short* __restrict__ xb, unsigned short* __restrict__ wf,
       unsigned short* __restrict__ wl, float* __restrict__ stats,
       float* __restrict__ zpg) {
    int tid = blockIdx.x * blockDim.x + threadIdx.x;
    if (blockIdx.x == 0 && threadIdx.x < 96) {
        if (threadIdx.x < 64) stats[threadIdx.x] = 0.0f;
        else                  zpg[threadIdx.x - 64] = 0.0f;   // 32 floats = 128B
    }
    if (tid < KT * 2 * 64) {
        int k = tid >> 7;
        int rem = tid & 127;
        int h = rem >> 6;
        int l = rem & 63;
        int kd0 = (l >> 4) * 8;
        int cc = h * 16 + (l & 15);
        #pragma unroll
        for (int j = 0; j < 8; j++)
            wf[tid * 8 + j] = f2bf(Wc[(k * CH + kd0 + j) * CH + cc]);
    } else if (tid < KT * 2 * 64 + 128) {
        int t2 = tid - KT * 2 * 64;
        int h = t2 >> 6;
        int l = t2 & 63;
        int n = l & 15;
        int kd0 = (l >> 4) * 8;
        #pragma unroll
        for (int j = 0; j < 8; j++)
            wl[t2 * 8 + j] = f2bf(Wlin[(h * 16 + n) * CH + kd0 + j]);
    }
    size_t i8 = (size_t)tid * 8;
    if (i8 < (size_t)NV * CH) {
        float4 a = *(const float4*)(x + i8);
        float4 b = *(const float4*)(x + i8 + 4);
        short8 o;
        o[0] = (short)f2bf(a.x); o[1] = (short)f2bf(a.y);
        o[2] = (short)f2bf(a.z); o[3] = (short)f2bf(a.w);
        o[4] = (short)f2bf(b.x); o[5] = (short)f2bf(b.y);
        o[6] = (short)f2bf(b.z); o[7] = (short)f2bf(b.w);
        *(short8*)(xb + i8) = o;
    }
}

// Issue 8 global_load_lds (2 taps x 4 tiles) for gather-group at SLOT.
// C0 = window-local first tap (compile-time), KG = global first tap (runtime,
// >124 masked to zero-page). NBARR = nb4 (this window) or nbn4 (next window).
#define GATHER8(SLOT, C0, KG, NBARR)                                          \
    do {                                                                      \
        _Pragma("unroll")                                                     \
        for (int jj = 0; jj < 2; jj++) {                                      \
            const int c_ = (C0) + jj;                                         \
            const int k_ = (KG) + jj;                                         \
            _Pragma("unroll")                                                 \
            for (int t_ = 0; t_ < 4; t_++) {                                  \
                int idx_ = __shfl(NBARR[t_][c_ & 3], ((c_ >> 2) << 4) | m, 64); \
                const char* src_ = xbB + ((size_t)(unsigned)idx_ << 6) + q16; \
                if ((idx_ < 0) || (k_ > 124)) src_ = zpgB + q16;              \
                gload_lds16(src_, lds_wb + (SLOT) * 8192 + (jj * 4 + t_) * 1024); \
            }                                                                 \
        }                                                                     \
    } while (0)

// One pipeline body, position P (0..7) of window W. Order (fence-separated by
// the vmcnt asm, which carries a "memory" clobber):
//  [nbr dwordx4 prefetch (P<4)] [gathers for group g+3] [wf for group g+1]
//  [s_waitcnt vmcnt(24)] [consume group g: 8 ds_read_b128 + 16 MFMA]
// vmcnt(24) is exact: exactly 3 gather-groups x 8 gl_lds are issued between
// group g's gathers and this wait (plain loads are NOT counted -> over-wait
// only, never under-wait).
#define BODY(P, SRC, W, WL)                                                   \
    do {                                                                      \
        if ((P) < 4)                                                          \
            nbn4[(P) & 3] = *(const int4a*)(nbr + rbase[(P) & 3] + (WL) * 16 + q4); \
        GATHER8(((P) + 3) & 3, (2 * ((P) + 3)) & 15, ((W) * 8 + (P) + 3) * 2, SRC); \
        {                                                                     \
            const int bk_ = ((P) + 1) & 1;                                    \
            const int kg_ = ((W) * 8 + (P) + 1) * 2;                          \
            _Pragma("unroll")                                                 \
            for (int jj = 0; jj < 2; jj++) {                                  \
                int kc_ = kg_ + jj; if (kc_ > 124) kc_ = 124;                 \
                Bf[bk_][jj][0] = *(const short8*)(wf + (size_t)(kc_ * 128 + lane) * 8); \
                Bf[bk_][jj][1] = *(const short8*)(wf + (size_t)(kc_ * 128 + 64 + lane) * 8); \
            }                                                                 \
        }                                                                     \
        asm volatile("s_waitcnt vmcnt(24)" ::: "memory");                     \
        {                                                                     \
            _Pragma("unroll")                                                 \
            for (int jj = 0; jj < 2; jj++) {                                  \
                _Pragma("unroll")                                             \
                for (int t_ = 0; t_ < 4; t_++) {                              \
                    short8 a_ = *(const short8*)(lds_lane + ((P) & 3) * 8192 + (jj * 4 + t_) * 1024); \
                    acc[t_][0] = __builtin_amdgcn_mfma_f32_16x16x32_bf16(a_, Bf[(P) & 1][jj][0], acc[t_][0], 0, 0, 0); \
                    acc[t_][1] = __builtin_amdgcn_mfma_f32_16x16x32_bf16(a_, Bf[(P) & 1][jj][1], acc[t_][1], 0, 0, 0); \
                }                                                             \
            }                                                                 \
        }                                                                     \
    } while (0)

// K2: gather-conv. Wave = 4 tiles of 16 voxels, 128 padded taps as 8 windows
// x 8 groups(2 taps). 4-deep LDS ring of 8KB group slots per wave.
__global__ __launch_bounds__(256) void
k_conv(const unsigned short* __restrict__ xb, const int* __restrict__ nbr,
       const unsigned short* __restrict__ wf, float* __restrict__ co,
       float* __restrict__ stats, const float* __restrict__ zpg) {
    const int lane = threadIdx.x & 63;
    const int wv = threadIdx.x >> 6;
    const int m = lane & 15;
    const int q = lane >> 4;
    const int q4 = q * 4;
    const int q16 = q * 16;
    const int vbase = (blockIdx.x * 4 + wv) * 64;

    __shared__ __attribute__((aligned(128))) char smem[131072]; // 4 waves x 32KB
    char* lds_wb = smem + wv * 32768;            // wave-uniform gl_lds base
    const char* lds_lane = lds_wb + lane * 16;   // each lane reads its own slot
    const char* xbB = (const char*)xb;
    const char* zpgB = (const char*)zpg;

    f32x4 acc[4][2];
    #pragma unroll
    for (int t = 0; t < 4; t++)
        #pragma unroll
        for (int h = 0; h < 2; h++)
            acc[t][h] = f32x4{0.f, 0.f, 0.f, 0.f};

    bool tval[4];
    int rbase[4];
    #pragma unroll
    for (int t = 0; t < 4; t++) {
        tval[t] = (vbase + t * 16) < NV;
        rbase[t] = tval[t] ? (vbase + t * 16 + m) * KT : 0;
    }

    short8 Bf[2][2][2];
    int4a nb4[4], nbn4[4];

    // ---- prologue: window-0 indices, gather groups 0..2, wf(0) ----
    #pragma unroll
    for (int t = 0; t < 4; t++)
        nb4[t] = *(const int4a*)(nbr + rbase[t] + q4);

    GATHER8(0, 0, 0, nb4);
    asm volatile("" ::: "memory");   // keep gather-group program order
    GATHER8(1, 2, 2, nb4);
    asm volatile("" ::: "memory");
    GATHER8(2, 4, 4, nb4);
    asm volatile("" ::: "memory");
    #pragma unroll
    for (int jj = 0; jj < 2; jj++) {
        Bf[0][jj][0] = *(const short8*)(wf + (size_t)(jj * 128 + lane) * 8);
        Bf[0][jj][1] = *(const short8*)(wf + (size_t)(jj * 128 + 64 + lane) * 8);
    }

    for (int w = 0; w < 8; w++) {
        const int wl2 = (w < 7) ? w + 1 : 0;   // w=7: dummy reload of window 0
        BODY(0, nb4,  w, wl2);
        BODY(1, nb4,  w, wl2);
        BODY(2, nb4,  w, wl2);
        BODY(3, nb4,  w, wl2);
        BODY(4, nb4,  w, wl2);
        BODY(5, nbn4, w, wl2);   // groups 8w+8.. live in next window
        BODY(6, nbn4, w, wl2);
        BODY(7, nbn4, w, wl2);
        #pragma unroll
        for (int t = 0; t < 4; t++) nb4[t] = nbn4[t];
    }

    float s0 = 0.f, s1 = 0.f, q0 = 0.f, q1 = 0.f;
    #pragma unroll
    for (int t = 0; t < 4; t++) {
        if (!tval[t]) continue;
        int v0 = vbase + t * 16 + q * 4;
        #pragma unroll
        for (int r = 0; r < 4; r++) {
            float a0 = acc[t][0][r], a1 = acc[t][1][r];
            co[(size_t)(v0 + r) * CH + m] = a0;
            co[(size_t)(v0 + r) * CH + 16 + m] = a1;
            s0 += a0; q0 += a0 * a0;
            s1 += a1; q1 += a1 * a1;
        }
    }
    s0 += __shfl_xor(s0, 16); s0 += __shfl_xor(s0, 32);
    s1 += __shfl_xor(s1, 16); s1 += __shfl_xor(s1, 32);
    q0 += __shfl_xor(q0, 16); q0 += __shfl_xor(q0, 32);
    q1 += __shfl_xor(q1, 16); q1 += __shfl_xor(q1, 32);
    if (q == 0) {
        atomicAdd(&stats[m],      s0);
        atomicAdd(&stats[16 + m], s1);
        atomicAdd(&stats[32 + m], q0);
        atomicAdd(&stats[48 + m], q1);
    }
}

// K3: finalize BN scale/shift. stats[64..95]=scale, stats[96..127]=shift.
__global__ void k_final(const float* __restrict__ gamma, const float* __restrict__ beta,
                        float* __restrict__ stats) {
    int c = threadIdx.x;
    if (c < CH) {
        float mean = stats[c] * (1.0f / NV);
        float var = stats[32 + c] * (1.0f / NV) - mean * mean;
        float sc = gamma[c] * rsqrtf(var + EPSBN);
        stats[64 + c] = sc;
        stats[96 + c] = beta[c] - mean * sc;
    }
}

// K4: in-place BN + ELU + MFMA linear on d_out. Wave = one 16-voxel tile/iter.
__global__ __launch_bounds__(256) void
k_epi(float* __restrict__ io, const unsigned short* __restrict__ wl,
      const float* __restrict__ blin, const float* __restrict__ stats) {
    const int lane = threadIdx.x & 63;
    const int wv = threadIdx.x >> 6;
    const int m = lane & 15;
    const int q = lane >> 4;

    short8 wl0 = *(const short8*)(wl + (size_t)lane * 8);
    short8 wl1 = *(const short8*)(wl + (size_t)(64 + lane) * 8);
    float ssc8[8], ssh8[8];
    #pragma unroll
    for (int j = 0; j < 8; j++) {
        ssc8[j] = stats[64 + q * 8 + j];
        ssh8[j] = stats[96 + q * 8 + j];
    }
    float bias0 = blin[m];
    float bias1 = blin[16 + m];

    const int wstep = gridDim.x * 4;
    for (int tile = blockIdx.x * 4 + wv; tile < NTILES; tile += wstep) {
        const int v0 = tile * 16;
        const float* p = io + (size_t)(v0 + m) * CH + q * 8;
        float4 e0 = *(const float4*)p;
        float4 e1 = *(const float4*)(p + 4);
        float e[8] = {e0.x, e0.y, e0.z, e0.w, e1.x, e1.y, e1.z, e1.w};
        short8 a;
        #pragma unroll
        for (int j = 0; j < 8; j++) {
            float f = e[j] * ssc8[j] + ssh8[j];
            f = f > 0.0f ? f : (__expf(f) - 1.0f);      // ELU alpha=1
            a[j] = (short)f2bf(f);
        }
        f32x4 z = {0.f, 0.f, 0.f, 0.f};
        f32x4 d0 = __builtin_amdgcn_mfma_f32_16x16x32_bf16(a, wl0, z, 0, 0, 0);
        f32x4 d1 = __builtin_amdgcn_mfma_f32_16x16x32_bf16(a, wl1, z, 0, 0, 0);
        #pragma unroll
        for (int r = 0; r < 4; r++) {
            io[(size_t)(v0 + q * 4 + r) * CH + m]      = d0[r] + bias0;
            io[(size_t)(v0 + q * 4 + r) * CH + 16 + m] = d1[r] + bias1;
        }
    }
}

extern "C" void kernel_launch(void* const* d_in, const int* in_sizes, int n_in,
                              void* d_out, int out_size, void* d_ws, size_t ws_size,
                              hipStream_t stream) {
    const float* x     = (const float*)d_in[0];
    const int*   nbr   = (const int*)d_in[1];
    const float* Wc    = (const float*)d_in[2];
    // d_in[3] = b_conv: canceled by BN mean subtraction.
    const float* gamma = (const float*)d_in[4];
    const float* beta  = (const float*)d_in[5];
    const float* Wlin  = (const float*)d_in[6];
    const float* blin  = (const float*)d_in[7];
    float* out = (float*)d_out;

    char* ws = (char*)d_ws;
    unsigned short* xb = (unsigned short*)ws;                               // 32 MB
    size_t off = (size_t)NV * CH * 2;
    unsigned short* wf = (unsigned short*)(ws + off);                       // 256 KB
    off += (size_t)KT * 128 * 8 * 2;
    unsigned short* wl = (unsigned short*)(ws + off);                       // 2 KB
    off += 128 * 8 * 2;
    float* stats = (float*)(ws + off);                                      // 512 B
    off += 512;
    float* zpg = (float*)(ws + off);                                        // 128 B zeros

    int prep_blocks = (int)(((size_t)NV * CH / 8 + 255) / 256);             // 7813
    hipLaunchKernelGGL(k_prep, dim3(prep_blocks), dim3(256), 0, stream,
                       x, Wc, Wlin, xb, wf, wl, stats, zpg);
    hipLaunchKernelGGL(k_conv, dim3((NV + 255) / 256), dim3(256), 0, stream,
                       xb, nbr, wf, out, stats, zpg);
    hipLaunchKernelGGL(k_final, dim3(1), dim3(64), 0, stream, gamma, beta, stats);
    hipLaunchKernelGGL(k_epi, dim3(1024), dim3(256), 0, stream, out, wl, blin, stats);
}